// Round 1
// baseline (36920.798 us; speedup 1.0000x reference)
//
#include <hip/hip_runtime.h>
#include <hip/hip_bf16.h>

#define BB   64
#define TENC 1024
#define DENC 256
#define HN   256
#define AN   128
#define NFC  10
#define EMBD 64
#define VN   96
#define TT   255
#define KX   576   // 64 emb + 256 ctx + 256 h

__device__ __forceinline__ float fsig(float x){ return 1.0f/(1.0f+__expf(-x)); }
__device__ __forceinline__ float ftanh(float x){ return 1.0f - 2.0f/(1.0f+__expf(2.0f*x)); }

// ---------------- one-time prep: packed weights, transposes, init state ----------------
__global__ void k_prep(const float* __restrict__ W_ih, const float* __restrict__ W_hh,
                       const float* __restrict__ b_ih, const float* __restrict__ b_hh,
                       const float* __restrict__ W_dec,
                       float* __restrict__ Wcomb, float* __restrict__ bias,
                       float* __restrict__ WdecT, float* __restrict__ e_init,
                       float* __restrict__ S_init)
{
    int tid = blockIdx.x*blockDim.x + threadIdx.x;
    int total = blockDim.x*gridDim.x;
    for (int i = tid; i < 1024*KX; i += total){
        int g = i / KX, k = i - g*KX;
        Wcomb[i] = (k < 320) ? W_ih[g*320 + k] : W_hh[g*256 + (k-320)];
    }
    for (int i = tid; i < 1024; i += total) bias[i] = b_ih[i] + b_hh[i];
    for (int i = tid; i < 256*128; i += total){ int u = i>>7, a = i&127; WdecT[i] = W_dec[a*256 + u]; }
    for (int i = tid; i < BB*TENC; i += total) e_init[i] = 1.0f;
    for (int i = tid; i < BB; i += total) S_init[i] = (float)TENC;
}

// ---------------- one-time: enc_proj[b,t,a] = sum_d enc[b,t,d] * W_enc[a,d] ----------------
__global__ __launch_bounds__(128) void k_encproj(const float* __restrict__ enc,
                                                 const float* __restrict__ W_enc,
                                                 float* __restrict__ enc_proj)
{
    __shared__ float rows[32][256];
    int r0 = blockIdx.x * 32;          // 2048 blocks cover 65536 rows
    for (int i = threadIdx.x; i < 32*256; i += 128)
        rows[i>>8][i&255] = enc[(size_t)r0*256 + i];
    __syncthreads();
    int a = threadIdx.x;               // 128 threads = A
    float acc[32];
    #pragma unroll
    for (int r=0;r<32;r++) acc[r]=0.f;
    const float* w = W_enc + a*256;
    for (int d=0; d<256; d+=4){
        float4 wv = *(const float4*)(w + d);
        #pragma unroll
        for (int r=0;r<32;r++){
            float4 rv = *(const float4*)(&rows[r][d]);
            acc[r] += wv.x*rv.x + wv.y*rv.y + wv.z*rv.z + wv.w*rv.w;
        }
    }
    for (int r=0;r<32;r++) enc_proj[(size_t)(r0+r)*AN + a] = acc[r];
}

// ---------------- per-step attention: hdec, conv, energy, exp, partial ctx/S ----------------
__global__ __launch_bounds__(256) void k_att(
    const float* __restrict__ enc, const float* __restrict__ enc_proj,
    const float* __restrict__ conv_w, const float* __restrict__ W_loc,
    const float* __restrict__ v_w, const int* __restrict__ lengths,
    const float* __restrict__ WdecT, const float* __restrict__ h_cur,
    const float* __restrict__ e_prev, float* __restrict__ e_new,
    const float* __restrict__ S_prev, float* __restrict__ pctx, float* __restrict__ pS)
{
    int b  = blockIdx.y;
    int ch = blockIdx.x;            // 4 chunks of 256 positions
    int t0 = ch*256;
    int tid = threadIdx.x;
    int lane = tid & 63, w64 = tid >> 6;

    __shared__ float hdec_s[128];
    __shared__ float part_s[256];
    __shared__ float ehalo[260];
    __shared__ float loc_s[256][11];
    __shared__ float wloc_s[128*11];
    __shared__ float cw_s[64];
    __shared__ float v_s[128];
    __shared__ float evals[256];

    if (tid < 50)  cw_s[tid] = conv_w[tid];
    if (tid < 128) v_s[tid]  = v_w[tid];
    for (int i = tid; i < 1280; i += 256){ int a=i/10, f=i-a*10; wloc_s[a*11+f] = W_loc[i]; }
    for (int i = tid; i < 260; i += 256){
        int g = t0 - 2 + i;
        ehalo[i] = (g >= 0 && g < TENC) ? e_prev[b*TENC + g] : 0.f;
    }
    {   // hdec partial: a = tid&127, half = tid>>7
        int a = tid & 127, half = tid >> 7;
        const float* hb = h_cur + b*HN + half*128;
        float acc = 0.f;
        for (int u=0; u<128; u++) acc += hb[u] * WdecT[(half*128+u)*AN + a];
        part_s[tid] = acc;
    }
    __syncthreads();
    if (tid < 128) hdec_s[tid] = part_s[tid] + part_s[tid+128];

    float invS = 1.0f / S_prev[b];
    {   // location conv for position p = tid (scaled by 1/S_prev)
        int p = tid;
        #pragma unroll
        for (int f=0; f<NFC; f++){
            float s = 0.f;
            #pragma unroll
            for (int k=0; k<5; k++) s += ehalo[p+k] * cw_s[f*5+k];
            loc_s[p][f] = s * invS;
        }
    }
    __syncthreads();

    int len_b = lengths[b];
    int nv = len_b - t0; nv = nv < 0 ? 0 : (nv > 256 ? 256 : nv);
    const float* epr = enc_proj + (size_t)(b*TENC + t0)*AN;

    for (int i=0; i<64; i++){
        int p = w64*64 + i;
        float e = 0.f;
        if (p < nv){
            int a0 = lane, a1 = lane + 64;
            const float* er = epr + p*AN;
            float x0 = er[a0] + hdec_s[a0];
            float x1 = er[a1] + hdec_s[a1];
            #pragma unroll
            for (int f=0; f<NFC; f++){
                float lf = loc_s[p][f];
                x0 += lf * wloc_s[a0*11+f];
                x1 += lf * wloc_s[a1*11+f];
            }
            float pe = v_s[a0]*ftanh(x0) + v_s[a1]*ftanh(x1);
            #pragma unroll
            for (int off=32; off; off>>=1) pe += __shfl_xor(pe, off);
            e = __expf(pe);          // bounded: |energy| <= sum|v| ~ 5.2
        }
        if (lane == 0) evals[p] = e;
    }
    __syncthreads();

    e_new[b*TENC + t0 + tid] = evals[tid];
    {   // partial S
        float se = evals[tid];
        #pragma unroll
        for (int off=32; off; off>>=1) se += __shfl_xor(se, off);
        if (lane == 0) part_s[w64] = se;
    }
    __syncthreads();
    if (tid == 0) pS[ch*BB + b] = part_s[0]+part_s[1]+part_s[2]+part_s[3];

    // partial (unnormalized) ctx: d = tid
    float acc = 0.f;
    const float* encb = enc + (size_t)(b*TENC + t0)*DENC;
    for (int p=0; p<nv; p++)
        acc += evals[p] * encb[p*DENC + tid];
    pctx[(ch*BB + b)*DENC + tid] = acc;
}

// ---------------- per-step cell: reduce ctx, logits(t-2), hid(t-1), gates(t), LSTM ----------------
__global__ __launch_bounds__(256) void k_cell(
    const float* __restrict__ pctx, const float* __restrict__ pS, float* __restrict__ S_glob,
    const int* __restrict__ targets, const float* __restrict__ emb,
    const float* __restrict__ Wcomb, const float* __restrict__ bias,
    const float* __restrict__ h_old, float* __restrict__ h_new, float* __restrict__ c_st,
    const float* __restrict__ out_w1, const float* __restrict__ out_b1,
    const float* __restrict__ hid_prev, float* __restrict__ hid_new,
    const float* __restrict__ out_w2, const float* __restrict__ out_b2,
    float* __restrict__ out, int t)
{
    int tid = threadIdx.x;
    int blk = blockIdx.x;   // 64
    bool do_reduce = (t >= 1 && t <= 255);
    bool do_gates  = (t <= 254);
    bool do_hid    = (t >= 1 && t <= 255);
    bool do_logits = (t >= 2);

    __shared__ float xh[16][580];
    __shared__ float invS_s[64];
    __shared__ float gates_s[16][17];
    __shared__ float hidp[16][4][5];

    if (do_reduce && tid < 64){
        float s = pS[tid] + pS[64+tid] + pS[128+tid] + pS[192+tid];
        invS_s[tid] = 1.0f / s;
        if (blk == 0) S_glob[tid] = s;
    }

    if (do_logits && tid < 128){
        int bb = tid & 63, ri = tid >> 6;
        int r = blk + ri*64;
        if (r < VN){
            const float* hp = hid_prev + bb*HN;
            const float* w2 = out_w2 + r*HN;
            float acc = out_b2[r];
            for (int u=0; u<HN; u+=4){
                float4 wv = *(const float4*)(w2+u);
                float4 hv = *(const float4*)(hp+u);
                acc += wv.x*hv.x + wv.y*hv.y + wv.z*hv.z + wv.w*hv.w;
            }
            out[((size_t)bb*TT + (t-2))*VN + r] = acc;
        }
    }
    __syncthreads();

    if (!(do_gates || do_hid)) return;

    for (int bt = 0; bt < 4; bt++){
        int b0 = bt*16;
        if (do_gates){
            for (int i = tid; i < 16*64; i += 256){
                int bl = i>>6, j = i&63;
                int tok = targets[(b0+bl)*256 + t];
                xh[bl][j] = emb[tok*EMBD + j];
            }
        }
        for (int i = tid; i < 16*256; i += 256){
            int bl = i>>8, d = i&255;
            float v = 0.f;
            if (do_reduce){
                int bg = b0 + bl;
                v = (pctx[(0*BB+bg)*DENC+d] + pctx[(1*BB+bg)*DENC+d] +
                     pctx[(2*BB+bg)*DENC+d] + pctx[(3*BB+bg)*DENC+d]) * invS_s[bg];
            }
            xh[bl][64+d] = v;
        }
        for (int i = tid; i < 16*256; i += 256){
            int bl = i>>8, d = i&255;
            xh[bl][320+d] = (t == 0) ? 0.f : h_old[(b0+bl)*HN + d];
        }
        __syncthreads();

        if (do_gates){
            int bl = tid & 15, row = tid >> 4;      // row: 4 gates x 4 units
            int gidx = row >> 2, ul = row & 3;
            int g = gidx*256 + blk*4 + ul;
            const float* wr = Wcomb + (size_t)g*KX;
            float acc = bias[g];
            for (int k=0; k<KX; k+=4){
                float4 wv = *(const float4*)(wr + k);
                float4 xv = *(const float4*)(&xh[bl][k]);
                acc += wv.x*xv.x + wv.y*xv.y + wv.z*xv.z + wv.w*xv.w;
            }
            gates_s[bl][row] = acc;
        }
        __syncthreads();

        if (do_gates && tid < 64){
            int bl = tid >> 2, ul = tid & 3;
            int bg = b0 + bl, ug = blk*4 + ul;
            float gi = gates_s[bl][0*4+ul], gf = gates_s[bl][1*4+ul];
            float gg = gates_s[bl][2*4+ul], go = gates_s[bl][3*4+ul];
            float cold = (t == 0) ? 0.f : c_st[bg*HN + ug];
            float cn = fsig(gf)*cold + fsig(gi)*ftanh(gg);
            c_st[bg*HN + ug] = cn;
            h_new[bg*HN + ug] = fsig(go)*ftanh(cn);
        }

        if (do_hid){
            int bl = tid >> 4, rl = (tid >> 2) & 3, kq = tid & 3;
            int r = blk*4 + rl;
            const float* w1 = out_w1 + (size_t)r*512 + (kq>>1)*256;
            const float* xsrc = (kq < 2) ? &xh[bl][320] : &xh[bl][64];
            int kk0 = (kq & 1)*128;
            float acc = 0.f;
            for (int k=kk0; k<kk0+128; k+=4){
                float4 wv = *(const float4*)(w1 + k);
                float4 xv = *(const float4*)(xsrc + k);
                acc += wv.x*xv.x + wv.y*xv.y + wv.z*xv.z + wv.w*xv.w;
            }
            hidp[bl][rl][kq] = acc;
        }
        __syncthreads();
        if (do_hid && tid < 64){
            int bl = tid >> 2, rl = tid & 3;
            int r = blk*4 + rl;
            float s = hidp[bl][rl][0]+hidp[bl][rl][1]+hidp[bl][rl][2]+hidp[bl][rl][3] + out_b1[r];
            hid_new[(b0+bl)*HN + r] = ftanh(s);
        }
        __syncthreads();
    }
}

extern "C" void kernel_launch(void* const* d_in, const int* in_sizes, int n_in,
                              void* d_out, int out_size, void* d_ws, size_t ws_size,
                              hipStream_t stream)
{
    const float* enc     = (const float*)d_in[0];
    const int*   lengths = (const int*)  d_in[1];
    const int*   targets = (const int*)  d_in[2];
    const float* emb     = (const float*)d_in[3];
    const float* W_ih    = (const float*)d_in[4];
    const float* W_hh    = (const float*)d_in[5];
    const float* b_ih    = (const float*)d_in[6];
    const float* b_hh    = (const float*)d_in[7];
    const float* conv_w  = (const float*)d_in[8];
    const float* W_enc   = (const float*)d_in[9];
    const float* W_dec   = (const float*)d_in[10];
    const float* W_loc   = (const float*)d_in[11];
    const float* v_w     = (const float*)d_in[12];
    const float* out_w1  = (const float*)d_in[13];
    const float* out_b1  = (const float*)d_in[14];
    const float* out_w2  = (const float*)d_in[15];
    const float* out_b2  = (const float*)d_in[16];
    float* out = (float*)d_out;

    float* ws = (float*)d_ws;
    size_t off = 0;
    auto alloc = [&](size_t n){ float* p = ws + off; off += n; return p; };
    float* enc_proj = alloc((size_t)BB*TENC*AN);
    float* Wcomb    = alloc(1024*KX);
    float* biasw    = alloc(1024);
    float* WdecT    = alloc(256*128);
    float* e0       = alloc(BB*TENC);
    float* e1       = alloc(BB*TENC);
    float* ebuf[2]  = {e0, e1};
    float* pctx     = alloc(4*BB*DENC);
    float* pS       = alloc(4*BB);
    float* S_glob   = alloc(BB);
    float* h0       = alloc(BB*HN);
    float* h1       = alloc(BB*HN);
    float* hbuf[2]  = {h0, h1};
    float* c_st     = alloc(BB*HN);
    float* hidA     = alloc(BB*HN);
    float* hidB     = alloc(BB*HN);
    float* hidbuf[2] = {hidA, hidB};
    if (off * sizeof(float) > ws_size) return;   // visible failure if ws too small

    k_prep<<<dim3(512), dim3(256), 0, stream>>>(W_ih, W_hh, b_ih, b_hh, W_dec,
                                                Wcomb, biasw, WdecT, e1, S_glob);
    k_encproj<<<dim3(2048), dim3(128), 0, stream>>>(enc, W_enc, enc_proj);

    for (int t = 0; t <= 256; t++){
        k_cell<<<dim3(64), dim3(256), 0, stream>>>(
            pctx, pS, S_glob, targets, emb, Wcomb, biasw,
            hbuf[(t+1)&1], hbuf[t&1], c_st,
            out_w1, out_b1, hidbuf[(t+1)&1], hidbuf[t&1],
            out_w2, out_b2, out, t);
        if (t <= 254){
            k_att<<<dim3(4,64), dim3(256), 0, stream>>>(
                enc, enc_proj, conv_w, W_loc, v_w, lengths, WdecT,
                hbuf[t&1], ebuf[(t+1)&1], ebuf[t&1], S_glob, pctx, pS);
        }
    }
}

// Round 2
// 11720.823 us; speedup vs baseline: 3.1500x; 3.1500x over previous
//
#include <hip/hip_runtime.h>
#include <hip/hip_bf16.h>

#define BB   64
#define TENC 1024
#define DENC 256
#define HN   256
#define AN   128
#define NFC  10
#define EMBD 64
#define VN   96
#define TT   255
#define KX   576   // 64 emb + 256 ctx + 256 h

__device__ __forceinline__ float fsig(float x){ return 1.0f/(1.0f+__expf(-x)); }
__device__ __forceinline__ float ftanh(float x){ return 1.0f - 2.0f/(1.0f+__expf(2.0f*x)); }

// ---------------- one-time prep ----------------
__global__ void k_prep(const float* __restrict__ W_ih, const float* __restrict__ W_hh,
                       const float* __restrict__ b_ih, const float* __restrict__ b_hh,
                       const float* __restrict__ W_dec,
                       float* __restrict__ Wcomb, float* __restrict__ bias,
                       float* __restrict__ WdecT, float* __restrict__ e_init,
                       float* __restrict__ S_init)
{
    int tid = blockIdx.x*blockDim.x + threadIdx.x;
    int total = blockDim.x*gridDim.x;
    for (int i = tid; i < 1024*KX; i += total){
        int g = i / KX, k = i - g*KX;
        Wcomb[i] = (k < 320) ? W_ih[g*320 + k] : W_hh[g*256 + (k-320)];
    }
    for (int i = tid; i < 1024; i += total) bias[i] = b_ih[i] + b_hh[i];
    for (int i = tid; i < 256*128; i += total){ int u = i>>7, a = i&127; WdecT[i] = W_dec[a*256 + u]; }
    for (int i = tid; i < BB*TENC; i += total) e_init[i] = 1.0f;
    for (int i = tid; i < BB; i += total) S_init[i] = (float)TENC;
}

// ---------------- one-time: enc_proj ----------------
__global__ __launch_bounds__(128) void k_encproj(const float* __restrict__ enc,
                                                 const float* __restrict__ W_enc,
                                                 float* __restrict__ enc_proj)
{
    __shared__ float rows[32][256];
    int r0 = blockIdx.x * 32;
    for (int i = threadIdx.x; i < 32*256; i += 128)
        rows[i>>8][i&255] = enc[(size_t)r0*256 + i];
    __syncthreads();
    int a = threadIdx.x;
    float acc[32];
    #pragma unroll
    for (int r=0;r<32;r++) acc[r]=0.f;
    const float* w = W_enc + a*256;
    for (int d=0; d<256; d+=4){
        float4 wv = *(const float4*)(w + d);
        #pragma unroll
        for (int r=0;r<32;r++){
            float4 rv = *(const float4*)(&rows[r][d]);
            acc[r] += wv.x*rv.x + wv.y*rv.y + wv.z*rv.z + wv.w*rv.w;
        }
    }
    for (int r=0;r<32;r++) enc_proj[(size_t)(r0+r)*AN + a] = acc[r];
}

// ---------------- per-step attention (grid 16 x 64, 256 thr) ----------------
__global__ __launch_bounds__(256) void k_att(
    const float* __restrict__ enc, const float* __restrict__ enc_proj,
    const float* __restrict__ conv_w, const float* __restrict__ W_loc,
    const float* __restrict__ v_w, const int* __restrict__ lengths,
    const float* __restrict__ WdecT, const float* __restrict__ h_cur,
    const float* __restrict__ e_prev, float* __restrict__ e_new,
    const float* __restrict__ SU_r, float* __restrict__ ctxU_w, float* __restrict__ SU_w)
{
    int b  = blockIdx.y;
    int ch = blockIdx.x;            // 16 chunks of 64 positions
    int t0 = ch*64;
    int tid = threadIdx.x;

    int len = lengths[b];
    int nv = len - t0; nv = nv < 0 ? 0 : (nv > 64 ? 64 : nv);
    if (nv == 0){                   // dead chunk: just keep e_new zeroed
        if (tid < 64) e_new[b*TENC + t0 + tid] = 0.f;
        return;
    }

    __shared__ float hdec_s[128];
    __shared__ float part_s[256];
    __shared__ float ehalo[68];
    __shared__ float loc_s[64][11];
    __shared__ float cw_s[52];
    __shared__ float evals[64];
    __shared__ float ep[64][33];
    __shared__ float wacc[4][256];

    if (tid < 50) cw_s[tid] = conv_w[tid];
    for (int i = tid; i < 68; i += 256){
        int g = t0 - 2 + i;
        ehalo[i] = (g >= 0 && g < TENC) ? e_prev[b*TENC + g] : 0.f;
    }
    {   // hdec partial over half the H dim
        int a = tid & 127, half = tid >> 7;
        const float* wd = WdecT + (size_t)(half*128)*AN + a;
        const float* hb = h_cur + b*HN + half*128;
        float s0 = 0.f, s1 = 0.f;
        for (int u = 0; u < 128; u += 2){
            s0 += hb[u]   * wd[(size_t)u*AN];
            s1 += hb[u+1] * wd[(size_t)(u+1)*AN];
        }
        part_s[tid] = s0 + s1;
    }
    __syncthreads();
    if (tid < 128) hdec_s[tid] = part_s[tid] + part_s[tid+128];
    float invS = 1.0f / SU_r[b];
    if (tid < 64){
        int p = tid;
        #pragma unroll
        for (int f = 0; f < NFC; f++){
            float s = 0.f;
            #pragma unroll
            for (int k = 0; k < 5; k++) s += ehalo[p+k] * cw_s[f*5+k];
            loc_s[p][f] = s * invS;
        }
    }
    __syncthreads();

    // phase 1: energy partials; thread = (pg: 8 positions) x (ag: 4 attention dims)
    {
        int ag = tid & 31, pg = tid >> 5;
        int a0 = ag*4;
        float4 hd = *(const float4*)&hdec_s[a0];
        float4 vv = *(const float4*)(v_w + a0);
        float4 wl[NFC];
        #pragma unroll
        for (int f = 0; f < NFC; f++){
            wl[f].x = W_loc[(a0+0)*NFC + f];
            wl[f].y = W_loc[(a0+1)*NFC + f];
            wl[f].z = W_loc[(a0+2)*NFC + f];
            wl[f].w = W_loc[(a0+3)*NFC + f];
        }
        for (int i = 0; i < 8; i++){
            int p = pg*8 + i;
            if (p < nv){
                float4 er = *(const float4*)(enc_proj + (size_t)(b*TENC + t0 + p)*AN + a0);
                float x0 = er.x + hd.x, x1 = er.y + hd.y, x2 = er.z + hd.z, x3 = er.w + hd.w;
                #pragma unroll
                for (int f = 0; f < NFC; f++){
                    float lf = loc_s[p][f];
                    x0 += lf * wl[f].x; x1 += lf * wl[f].y;
                    x2 += lf * wl[f].z; x3 += lf * wl[f].w;
                }
                ep[p][ag] = vv.x*ftanh(x0) + vv.y*ftanh(x1) + vv.z*ftanh(x2) + vv.w*ftanh(x3);
            }
        }
    }
    __syncthreads();

    // phase 2: reduce 32 partials per position, exp, store e, reduce S
    if (tid < 64){
        int p = tid;
        float e = 0.f;
        if (p < nv){
            float s0 = 0.f, s1 = 0.f;
            #pragma unroll
            for (int j = 0; j < 32; j += 2){ s0 += ep[p][j]; s1 += ep[p][j+1]; }
            e = __expf(s0 + s1);     // bounded: |energy| <= sum|v| ~ 5.2
        }
        evals[p] = e;
        e_new[b*TENC + t0 + p] = e;
        float se = e;
        #pragma unroll
        for (int off = 32; off; off >>= 1) se += __shfl_xor(se, off);
        if (tid == 0) atomicAdd(SU_w + b, se);
    }
    __syncthreads();

    // phase 3: unnormalized ctx partial, thread = (pq: p stride 4) x (dq: 4 dims)
    {
        int dq = tid & 63, pq = tid >> 6;
        float4 acc = {0.f,0.f,0.f,0.f};
        for (int i = 0; i < 16; i++){
            int p = pq + i*4;
            if (p < nv){
                float ev = evals[p];
                float4 ex = *(const float4*)(enc + (size_t)(b*TENC + t0 + p)*DENC + dq*4);
                acc.x += ev*ex.x; acc.y += ev*ex.y; acc.z += ev*ex.z; acc.w += ev*ex.w;
            }
        }
        *(float4*)&wacc[pq][dq*4] = acc;
    }
    __syncthreads();
    {
        int d = tid;
        float s = wacc[0][d] + wacc[1][d] + wacc[2][d] + wacc[3][d];
        atomicAdd(ctxU_w + b*DENC + d, s);
    }
}

// ---------------- per-step cell (grid 344, 256 thr) ----------------
// blocks [0,256): gates+LSTM   (bg = blk>>6 batch-group of 16, ug = blk&63 -> 4 units)
// blocks [256,320): hid        (bg = (blk-256)>>4, rg = (blk-256)&15 -> 16 rows)
// blocks [320,344): logits     (lb = blk-320: vg = lb%12 -> 8 v-rows, bgr = lb/12 -> 32 batches)
__global__ __launch_bounds__(256) void k_cell(
    const float* __restrict__ ctxU_r, const float* __restrict__ SU_r,
    float* __restrict__ ctxU_w, float* __restrict__ SU_w,
    const int* __restrict__ targets, const float* __restrict__ emb,
    const float* __restrict__ Wcomb, const float* __restrict__ bias,
    const float* __restrict__ h_old, float* __restrict__ h_new, float* __restrict__ c_st,
    const float* __restrict__ out_w1, const float* __restrict__ out_b1,
    const float* __restrict__ hid_prev, float* __restrict__ hid_new,
    const float* __restrict__ out_w2, const float* __restrict__ out_b2,
    float* __restrict__ out, int t)
{
    int blk = blockIdx.x, tid = threadIdx.x;
    bool do_reduce = (t >= 1 && t <= 255);
    bool do_gates  = (t <= 254);
    bool do_hid    = (t >= 1 && t <= 255);
    bool do_logits = (t >= 2);

    __shared__ float smem[16*580];          // aliased by all roles
    __shared__ float invS_s[32];
    __shared__ float gates_s[16][17];

    if (blk < 256){
        int bg = blk >> 6, ug = blk & 63;
        int b0 = bg*16;
        if (ug == 1 && t <= 254){           // zero next-step accumulators for this bg
            for (int i = tid; i < 16*DENC; i += 256) ctxU_w[b0*DENC + i] = 0.f;
            if (tid < 16) SU_w[b0 + tid] = 0.f;
        }
        if (!do_gates) return;
        float (*xh)[580] = (float(*)[580])smem;
        if (tid < 16) invS_s[tid] = do_reduce ? 1.0f/SU_r[b0+tid] : 0.f;
        for (int i = tid; i < 16*EMBD; i += 256){
            int bl = i>>6, j = i&63;
            int tok = targets[(b0+bl)*256 + t];
            xh[bl][j] = emb[tok*EMBD + j];
        }
        for (int i = tid; i < 16*HN; i += 256){
            int bl = i>>8, d = i&255;
            xh[bl][320+d] = (t == 0) ? 0.f : h_old[(b0+bl)*HN + d];
        }
        __syncthreads();
        for (int i = tid; i < 16*DENC; i += 256){
            int bl = i>>8, d = i&255;
            xh[bl][64+d] = do_reduce ? ctxU_r[(b0+bl)*DENC + d] * invS_s[bl] : 0.f;
        }
        __syncthreads();
        {
            int bl = tid & 15, row = tid >> 4;
            int gidx = row >> 2, ul = row & 3;
            int g = gidx*256 + ug*4 + ul;
            const float* wr = Wcomb + (size_t)g*KX;
            float a0 = bias[g], a1 = 0.f, a2 = 0.f, a3 = 0.f;
            for (int k = 0; k < KX; k += 4){
                float4 wv = *(const float4*)(wr + k);
                float4 xv = *(const float4*)(&xh[bl][k]);
                a0 += wv.x*xv.x; a1 += wv.y*xv.y; a2 += wv.z*xv.z; a3 += wv.w*xv.w;
            }
            gates_s[bl][row] = (a0+a1)+(a2+a3);
        }
        __syncthreads();
        if (tid < 64){
            int bl = tid >> 2, ul = tid & 3;
            int bgl = b0 + bl, ugl = ug*4 + ul;
            float gi = gates_s[bl][0*4+ul], gf = gates_s[bl][1*4+ul];
            float gg = gates_s[bl][2*4+ul], go = gates_s[bl][3*4+ul];
            float cold = (t == 0) ? 0.f : c_st[bgl*HN + ugl];
            float cn = fsig(gf)*cold + fsig(gi)*ftanh(gg);
            c_st[bgl*HN + ugl] = cn;
            h_new[bgl*HN + ugl] = fsig(go)*ftanh(cn);
        }
        return;
    }

    if (blk < 320){
        if (!do_hid) return;
        int hb = blk - 256;
        int bg = hb >> 4, rg = hb & 15;
        int b0 = bg*16;
        float (*xh2)[516] = (float(*)[516])smem;
        if (tid < 16) invS_s[tid] = 1.0f/SU_r[b0+tid];
        for (int i = tid; i < 16*HN; i += 256){
            int bl = i>>8, d = i&255;
            xh2[bl][d] = h_old[(b0+bl)*HN + d];
        }
        __syncthreads();
        for (int i = tid; i < 16*DENC; i += 256){
            int bl = i>>8, d = i&255;
            xh2[bl][256+d] = ctxU_r[(b0+bl)*DENC + d] * invS_s[bl];
        }
        __syncthreads();
        {
            int bl = tid & 15, rl = tid >> 4;
            int r = rg*16 + rl;
            const float* w1 = out_w1 + (size_t)r*512;
            float a0 = 0.f, a1 = 0.f, a2 = 0.f, a3 = 0.f;
            for (int k = 0; k < 512; k += 4){
                float4 wv = *(const float4*)(w1 + k);
                float4 xv = *(const float4*)(&xh2[bl][k]);
                a0 += wv.x*xv.x; a1 += wv.y*xv.y; a2 += wv.z*xv.z; a3 += wv.w*xv.w;
            }
            hid_new[(b0+bl)*HN + r] = ftanh(((a0+a1)+(a2+a3)) + out_b1[r]);
        }
        return;
    }

    {
        if (!do_logits) return;
        int lb = blk - 320;
        int vg = lb % 12, bgr = lb / 12;
        int b0 = bgr*32;
        float (*hs)[260] = (float(*)[260])smem;
        for (int i = tid; i < 32*HN; i += 256){
            int bl = i>>8, d = i&255;
            hs[bl][d] = hid_prev[(b0+bl)*HN + d];
        }
        __syncthreads();
        {
            int bl = tid & 31, vr = tid >> 5;
            int v = vg*8 + vr;
            const float* w2 = out_w2 + (size_t)v*HN;
            float a0 = 0.f, a1 = 0.f, a2 = 0.f, a3 = 0.f;
            for (int k = 0; k < HN; k += 4){
                float4 wv = *(const float4*)(w2 + k);
                float4 xv = *(const float4*)(&hs[bl][k]);
                a0 += wv.x*xv.x; a1 += wv.y*xv.y; a2 += wv.z*xv.z; a3 += wv.w*xv.w;
            }
            out[((size_t)(b0+bl)*TT + (t-2))*VN + v] = ((a0+a1)+(a2+a3)) + out_b2[v];
        }
    }
}

extern "C" void kernel_launch(void* const* d_in, const int* in_sizes, int n_in,
                              void* d_out, int out_size, void* d_ws, size_t ws_size,
                              hipStream_t stream)
{
    const float* enc     = (const float*)d_in[0];
    const int*   lengths = (const int*)  d_in[1];
    const int*   targets = (const int*)  d_in[2];
    const float* emb     = (const float*)d_in[3];
    const float* W_ih    = (const float*)d_in[4];
    const float* W_hh    = (const float*)d_in[5];
    const float* b_ih    = (const float*)d_in[6];
    const float* b_hh    = (const float*)d_in[7];
    const float* conv_w  = (const float*)d_in[8];
    const float* W_enc   = (const float*)d_in[9];
    const float* W_dec   = (const float*)d_in[10];
    const float* W_loc   = (const float*)d_in[11];
    const float* v_w     = (const float*)d_in[12];
    const float* out_w1  = (const float*)d_in[13];
    const float* out_b1  = (const float*)d_in[14];
    const float* out_w2  = (const float*)d_in[15];
    const float* out_b2  = (const float*)d_in[16];
    float* out = (float*)d_out;

    float* ws = (float*)d_ws;
    size_t off = 0;
    auto alloc = [&](size_t n){ float* p = ws + off; off += n; return p; };
    float* enc_proj = alloc((size_t)BB*TENC*AN);
    float* Wcomb    = alloc(1024*KX);
    float* biasw    = alloc(1024);
    float* WdecT    = alloc(256*128);
    float* e0       = alloc(BB*TENC);
    float* e1       = alloc(BB*TENC);
    float* ebuf[2]  = {e0, e1};
    float* ctxU0    = alloc(BB*DENC);
    float* ctxU1    = alloc(BB*DENC);
    float* ctxU[2]  = {ctxU0, ctxU1};
    float* SU0      = alloc(BB);
    float* SU1      = alloc(BB);
    float* SU[2]    = {SU0, SU1};
    float* h0       = alloc(BB*HN);
    float* h1       = alloc(BB*HN);
    float* hbuf[2]  = {h0, h1};
    float* c_st     = alloc(BB*HN);
    float* hidA     = alloc(BB*HN);
    float* hidB     = alloc(BB*HN);
    float* hidbuf[2] = {hidA, hidB};
    if (off * sizeof(float) > ws_size) return;

    k_prep<<<dim3(512), dim3(256), 0, stream>>>(W_ih, W_hh, b_ih, b_hh, W_dec,
                                                Wcomb, biasw, WdecT, e1, SU1);
    k_encproj<<<dim3(2048), dim3(128), 0, stream>>>(enc, W_enc, enc_proj);

    for (int t = 0; t <= 256; t++){
        k_cell<<<dim3(344), dim3(256), 0, stream>>>(
            ctxU[(t+1)&1], SU[(t+1)&1], ctxU[t&1], SU[t&1],
            targets, emb, Wcomb, biasw,
            hbuf[(t+1)&1], hbuf[t&1], c_st,
            out_w1, out_b1, hidbuf[(t+1)&1], hidbuf[t&1],
            out_w2, out_b2, out, t);
        if (t <= 254){
            k_att<<<dim3(16,64), dim3(256), 0, stream>>>(
                enc, enc_proj, conv_w, W_loc, v_w, lengths, WdecT,
                hbuf[t&1], ebuf[(t+1)&1], ebuf[t&1],
                SU[(t+1)&1], ctxU[t&1], SU[t&1]);
        }
    }
}